// Round 16
// baseline (181.487 us; speedup 1.0000x reference)
//
#include <hip/hip_runtime.h>
#include <stdint.h>

typedef uint16_t u16;
typedef __bf16 bf16x8 __attribute__((ext_vector_type(8)));
typedef float f32x4 __attribute__((ext_vector_type(4)));
typedef uint16_t u16x4 __attribute__((ext_vector_type(4)));
typedef uint16_t u16x8 __attribute__((ext_vector_type(8)));

typedef __attribute__((address_space(1))) void as1_void;
typedef __attribute__((address_space(3))) void as3_void;

__device__ __forceinline__ float bf2f(u16 b) {
    union { uint32_t u; float f; } v; v.u = ((uint32_t)b) << 16; return v.f;
}
__device__ __forceinline__ u16 f2bf(float f) {
    union { float f; uint32_t u; } v; v.f = f;
    uint32_t u = v.u;
    u += 0x7fffu + ((u >> 16) & 1u);   // RNE
    return (u16)(u >> 16);
}
__device__ __forceinline__ void gload_lds16(const u16* g, u16* l) {
    __builtin_amdgcn_global_load_lds((as1_void*)g, (as3_void*)l, 16, 0, 0);
}

// ---------------------------------------------------------------------------
// Fused fp32->bf16 convert of x, w_qkv, w_proj in one launch (r5-proven).
// ---------------------------------------------------------------------------
__global__ __launch_bounds__(256) void cvt3(
    const float* __restrict__ x,  u16* __restrict__ xb,
    const float* __restrict__ wq, u16* __restrict__ wqb,
    const float* __restrict__ wp, u16* __restrict__ wpb)
{
    const float* src; u16* dst; int base, nb;
    const int b = blockIdx.x;
    if (b < 1024)      { src = x;  dst = xb;  base = b;        nb = 1024; }
    else if (b < 1072) { src = wq; dst = wqb; base = b - 1024; nb = 48;   }
    else               { src = wp; dst = wpb; base = b - 1072; nb = 16;   }
    size_t i = ((size_t)base * 256 + threadIdx.x) * 8;
    const size_t stride = (size_t)nb * 256 * 8;
    #pragma unroll
    for (int it = 0; it < 8; ++it, i += stride) {
        f32x4 a = *(const f32x4*)(src + i);
        f32x4 c = *(const f32x4*)(src + i + 4);
        u16x8 o;
        o[0] = f2bf(a[0]); o[1] = f2bf(a[1]); o[2] = f2bf(a[2]); o[3] = f2bf(a[3]);
        o[4] = f2bf(c[0]); o[5] = f2bf(c[1]); o[6] = f2bf(c[2]); o[7] = f2bf(c[3]);
        *(u16x8*)(dst + i) = o;
    }
}

// ---------------------------------------------------------------------------
// Pipelined bf16 GEMM (r15-verified structure): C = A @ B^T (+bias).
// 128x128 tile, BK=32, 4 waves, 4 LDS buffers (64KB -> 2 blocks/CU),
// stage-3-ahead global_load_lds, ONE barrier per K-tile.
// Body(t): STAGE(t+3) | MFMA(t) (operands pre-read) | reads(t+1) |
// lgkmcnt(0) vmcnt(4) barrier. Invariant: barrier_t => S(t+1) landed on all
// waves (each wave's vmcnt(4) leaves only S(t+2) outstanding; 4 loads/STAGE).
// LDS rotation: slot = (chunk + (row>>1)) & 3 -> 2 lanes/bank-group (free).
// ---------------------------------------------------------------------------
template<int NT, bool C_F32, bool NORMK>   // NT = K/32
__global__ __launch_bounds__(256, 2) void gemm_pipe(
    const u16* __restrict__ A, int lda,
    const u16* __restrict__ B, int ldb,
    const float* __restrict__ bias,
    void* __restrict__ Cv, int ldc)
{
    __shared__ u16 lA[4][128 * 32];   // 8 KB each
    __shared__ u16 lB[4][128 * 32];

    const int tid  = threadIdx.x;
    const int lane = tid & 63;
    const int wave = tid >> 6;
    const int wr = (wave >> 1) * 64;
    const int wc = (wave & 1) * 64;
    const int cl = lane & 15;
    const int gr = lane >> 4;

    // T1: XCD chunked swizzle (grid % 8 == 0)
    int fid = blockIdx.y * gridDim.x + blockIdx.x;
    const int nwg = gridDim.x * gridDim.y;
    fid = (fid & 7) * (nwg >> 3) + (fid >> 3);
    const int row0 = (fid / gridDim.x) * 128;
    const int col0 = (fid % gridDim.x) * 128;

    f32x4 acc[4][4] = {};

    auto STAGE = [&](int t, int d) {   // 2 A + 2 B gload_lds per thread
        const int k0 = t * 32;
        #pragma unroll
        for (int i = 0; i < 2; ++i) {
            const int id  = i * 256 + tid;
            const int row = id >> 2;
            const int sch = ((id & 3) - ((row >> 1) & 3)) & 3;
            gload_lds16(A + (size_t)(row0 + row) * lda + k0 + sch * 8, &lA[d][id * 8]);
            gload_lds16(B + (size_t)(col0 + row) * ldb + k0 + sch * 8, &lB[d][id * 8]);
        }
    };

    bf16x8 af[4], bfv[4];
    auto READS = [&](int t) {
        const u16* la = lA[t & 3];
        const u16* lb = lB[t & 3];
        #pragma unroll
        for (int m = 0; m < 4; ++m) {
            const int ra = wr + m * 16 + cl;
            af[m] = *(const bf16x8*)&la[ra * 32 + ((gr + (ra >> 1)) & 3) * 8];
        }
        #pragma unroll
        for (int n = 0; n < 4; ++n) {
            const int rb = wc + n * 16 + cl;
            bfv[n] = *(const bf16x8*)&lb[rb * 32 + ((gr + (rb >> 1)) & 3) * 8];
        }
    };

    // prologue
    STAGE(0, 0); STAGE(1, 1); STAGE(2, 2);
    asm volatile("s_waitcnt vmcnt(4)" ::: "memory");   // S0,S1 landed (S2 may fly)
    __builtin_amdgcn_s_barrier();                      // all waves: S0,S1 visible
    READS(0);

    #pragma unroll
    for (int t = 0; t < NT; ++t) {
        if (t + 3 < NT) STAGE(t + 3, (t + 3) & 3);
        __builtin_amdgcn_s_setprio(1);
        #pragma unroll
        for (int m = 0; m < 4; ++m)
            #pragma unroll
            for (int n = 0; n < 4; ++n)
                acc[m][n] = __builtin_amdgcn_mfma_f32_16x16x32_bf16(af[m], bfv[n], acc[m][n], 0, 0, 0);
        __builtin_amdgcn_s_setprio(0);
        if (t + 1 < NT) READS(t + 1);                  // overlaps MFMA(t) pipe
        if (t < NT - 1) {
            asm volatile("s_waitcnt lgkmcnt(0)" ::: "memory");   // my reads captured
            if (t + 3 < NT) asm volatile("s_waitcnt vmcnt(4)" ::: "memory");  // S(t+2) landed
            else            asm volatile("s_waitcnt vmcnt(0)" ::: "memory");  // tail drain
            __builtin_amdgcn_s_barrier();
        }
    }

    if constexpr (NORMK) {
        if (col0 + wc >= 512 && col0 + wc < 1024) {
            #pragma unroll
            for (int m = 0; m < 4; ++m)
                #pragma unroll
                for (int j = 0; j < 4; ++j) {
                    float ss = 0.f;
                    #pragma unroll
                    for (int n = 0; n < 4; ++n) ss += acc[m][n][j] * acc[m][n][j];
                    ss += __shfl_xor(ss, 1);
                    ss += __shfl_xor(ss, 2);
                    ss += __shfl_xor(ss, 4);
                    ss += __shfl_xor(ss, 8);
                    const float scl = 1.f / fmaxf(sqrtf(ss), 1e-12f);
                    #pragma unroll
                    for (int n = 0; n < 4; ++n) acc[m][n][j] *= scl;
                }
        }
    }

    #pragma unroll
    for (int m = 0; m < 4; ++m) {
        const int r = row0 + wr + m * 16 + gr * 4;
        #pragma unroll
        for (int n = 0; n < 4; ++n) {
            const int c = col0 + wc + n * 16 + cl;
            const float bv = bias ? bias[c] : 0.f;
            #pragma unroll
            for (int j = 0; j < 4; ++j) {
                const float val = acc[m][n][j] + bv;
                if constexpr (C_F32) ((float*)Cv)[(size_t)(r + j) * ldc + c] = val;
                else                 ((u16*)Cv)[(size_t)(r + j) * ldc + c] = f2bf(val);
            }
        }
    }
}

// ---------------------------------------------------------------------------
// fp32-input fallback GEMM (register staging + convert). Used only if ws too small.
// ---------------------------------------------------------------------------
template<bool A_F32, bool C_F32, bool NORMK>
__global__ __launch_bounds__(256) void gemm_bt_f32(
    const void* __restrict__ Av, int lda,
    const float* __restrict__ B, int ldb,
    const float* __restrict__ bias,
    void* __restrict__ Cv, int ldc,
    int K)
{
    __shared__ u16 lA[128 * 32];
    __shared__ u16 lB[128 * 32];

    const int tid  = threadIdx.x;
    const int lane = tid & 63;
    const int wave = tid >> 6;
    const int wr   = (wave >> 1) * 64;
    const int wc   = (wave & 1) * 64;
    const int row0 = blockIdx.y * 128;
    const int col0 = blockIdx.x * 128;

    f32x4 acc[4][4] = {};

    for (int k0 = 0; k0 < K; k0 += 32) {
        #pragma unroll
        for (int i = 0; i < 4; ++i) {
            const int idx = i * 256 + tid;
            const int r = idx >> 3;
            const int p = (idx & 7) * 4;
            u16x4 a4, b4;
            if constexpr (A_F32) {
                const float* Af = (const float*)Av;
                f32x4 va = *(const f32x4*)(Af + (size_t)(row0 + r) * lda + k0 + p);
                a4[0] = f2bf(va[0]); a4[1] = f2bf(va[1]); a4[2] = f2bf(va[2]); a4[3] = f2bf(va[3]);
            } else {
                const u16* Ab = (const u16*)Av;
                a4 = *(const u16x4*)(Ab + (size_t)(row0 + r) * lda + k0 + p);
            }
            {
                f32x4 vb = *(const f32x4*)(B + (size_t)(col0 + r) * ldb + k0 + p);
                b4[0] = f2bf(vb[0]); b4[1] = f2bf(vb[1]); b4[2] = f2bf(vb[2]); b4[3] = f2bf(vb[3]);
            }
            *(u16x4*)&lA[r * 32 + p] = a4;
            *(u16x4*)&lB[r * 32 + p] = b4;
        }
        __syncthreads();

        bf16x8 af[4], bfv[4];
        #pragma unroll
        for (int m = 0; m < 4; ++m)
            af[m] = *(const bf16x8*)(lA + (wr + m * 16 + (lane & 15)) * 32 + (lane >> 4) * 8);
        #pragma unroll
        for (int n = 0; n < 4; ++n)
            bfv[n] = *(const bf16x8*)(lB + (wc + n * 16 + (lane & 15)) * 32 + (lane >> 4) * 8);
        #pragma unroll
        for (int m = 0; m < 4; ++m)
            #pragma unroll
            for (int n = 0; n < 4; ++n)
                acc[m][n] = __builtin_amdgcn_mfma_f32_16x16x32_bf16(af[m], bfv[n], acc[m][n], 0, 0, 0);
        __syncthreads();
    }

    if constexpr (NORMK) {
        if (col0 >= 512 && col0 < 1024) {
            #pragma unroll
            for (int m = 0; m < 4; ++m)
                #pragma unroll
                for (int j = 0; j < 4; ++j) {
                    float ss = 0.f;
                    #pragma unroll
                    for (int n = 0; n < 4; ++n) ss += acc[m][n][j] * acc[m][n][j];
                    ss += __shfl_xor(ss, 1);
                    ss += __shfl_xor(ss, 2);
                    ss += __shfl_xor(ss, 4);
                    ss += __shfl_xor(ss, 8);
                    const float scl = 1.f / fmaxf(sqrtf(ss), 1e-12f);
                    #pragma unroll
                    for (int n = 0; n < 4; ++n) acc[m][n][j] *= scl;
                }
        }
    }

    #pragma unroll
    for (int m = 0; m < 4; ++m) {
        const int r = row0 + wr + m * 16 + ((lane >> 4) << 2);
        #pragma unroll
        for (int n = 0; n < 4; ++n) {
            const int c = col0 + wc + n * 16 + (lane & 15);
            const float bv = bias ? bias[c] : 0.f;
            #pragma unroll
            for (int j = 0; j < 4; ++j) {
                const float val = acc[m][n][j] + bv;
                if constexpr (C_F32) ((float*)Cv)[(size_t)(r + j) * ldc + c] = val;
                else                 ((u16*)Cv)[(size_t)(r + j) * ldc + c] = f2bf(val);
            }
        }
    }
}

// ---------------------------------------------------------------------------
// Local attention, online-softmax over two 128-key chunks. Chunk 1's K/V are
// PREFETCHED INTO REGISTERS during chunk-0 staging (chunk 1 is never padded:
// tkc1 = tq0 >= 0) and written to LDS after chunk-0's post-PV barrier (T14).
// ---------------------------------------------------------------------------
__global__ __launch_bounds__(512, 4) void attn_kernel(const u16* qkv, u16* o)
{
    constexpr int CC = 1536;
    constexpr int NTOK = 8192;
    constexpr int KP = 72;
    constexpr int VP = 136;
    constexpr int PP = 136;
    __shared__ u16 kn[128 * KP];
    __shared__ u16 vT[64 * VP];
    __shared__ u16 Pl[128 * PP];

    const int tid  = threadIdx.x;
    const int lane = tid & 63;
    const int wave = tid >> 6;
    const int cl = lane & 15;
    const int gr = lane >> 4;

    int blk = blockIdx.x;
    blk = (blk & 7) * (gridDim.x >> 3) + (blk >> 3);

    const int iw  = blk & 63;
    const int h   = (blk >> 6) & 7;
    const int b   = blk >> 9;

    const int tq0 = iw * 128;
    const int tkc0 = tq0 - 128;
    const int tkc1 = tq0;
    const size_t rowbase = (size_t)b * NTOK;
    const u16* qbase = qkv + rowbase * CC + h * 64;
    const u16* kbase = qbase + 512;
    const u16* vbase = qbase + 1024;

    const int wrow = wave * 16;
    bf16x8 qf[2];
    #pragma unroll
    for (int kk = 0; kk < 2; ++kk)
        qf[kk] = *(const bf16x8*)(qbase + (size_t)(tq0 + wrow + cl) * CC + kk * 32 + gr * 8);

    f32x4 oacc[4] = {};
    float m_run[4] = {-3.0e38f, -3.0e38f, -3.0e38f, -3.0e38f};
    float l_run[4] = {0.f, 0.f, 0.f, 0.f};

    // one K/V-chunk of compute: QK^T -> mask+online softmax -> Pl -> PV
    auto CHUNK = [&](int tkc) {
        f32x4 s[8] = {};
        #pragma unroll
        for (int n = 0; n < 8; ++n)
            #pragma unroll
            for (int kk = 0; kk < 2; ++kk) {
                const bf16x8 kf = *(const bf16x8*)&kn[(n * 16 + cl) * KP + kk * 32 + gr * 8];
                s[n] = __builtin_amdgcn_mfma_f32_16x16x32_bf16(qf[kk], kf, s[n], 0, 0, 0);
            }
        float pmax[4] = {-3.0e38f, -3.0e38f, -3.0e38f, -3.0e38f};
        #pragma unroll
        for (int n = 0; n < 8; ++n) {
            const int tkk = tkc + n * 16 + cl;
            const bool pad = tkk < 0;
            #pragma unroll
            for (int j = 0; j < 4; ++j) {
                const int tq = tq0 + wrow + gr * 4 + j;
                float sv = s[n][j] * 0.125f;
                const int rel = tkk - tq;
                sv = (rel == 0) ? -5.0e4f : sv;
                sv = (rel > 0 || pad) ? -6.0e4f : sv;
                s[n][j] = sv;
                pmax[j] = fmaxf(pmax[j], sv);
            }
        }
        float cold[4];
        #pragma unroll
        for (int j = 0; j < 4; ++j) {
            pmax[j] = fmaxf(pmax[j], __shfl_xor(pmax[j], 1));
            pmax[j] = fmaxf(pmax[j], __shfl_xor(pmax[j], 2));
            pmax[j] = fmaxf(pmax[j], __shfl_xor(pmax[j], 4));
            pmax[j] = fmaxf(pmax[j], __shfl_xor(pmax[j], 8));
            const float mn = fmaxf(m_run[j], pmax[j]);
            cold[j] = __expf(m_run[j] - mn);
            m_run[j] = mn;
            l_run[j] *= cold[j];
        }
        #pragma unroll
        for (int n = 0; n < 8; ++n)
            #pragma unroll
            for (int j = 0; j < 4; ++j) {
                const float p = __expf(s[n][j] - m_run[j]);
                s[n][j] = p;
                l_run[j] += p;
            }
        #pragma unroll
        for (int n = 0; n < 4; ++n) {
            f32x4 t = oacc[n];
            t[0] *= cold[0]; t[1] *= cold[1]; t[2] *= cold[2]; t[3] *= cold[3];
            oacc[n] = t;
        }
        #pragma unroll
        for (int n = 0; n < 8; ++n)
            #pragma unroll
            for (int j = 0; j < 4; ++j)
                Pl[(wrow + gr * 4 + j) * PP + n * 16 + cl] = f2bf(s[n][j]);
        __syncthreads();
        #pragma unroll
        for (int kk = 0; kk < 4; ++kk) {
            const bf16x8 pa = *(const bf16x8*)&Pl[(wrow + cl) * PP + kk * 32 + gr * 8];
            #pragma unroll
            for (int n = 0; n < 4; ++n) {
                const bf16x8 vb = *(const bf16x8*)&vT[(n * 16 + cl) * VP + kk * 32 + gr * 8];
                oacc[n] = __builtin_amdgcn_mfma_f32_16x16x32_bf16(pa, vb, oacc[n], 0, 0, 0);
            }
        }
    };

    // ---- stage chunk 0 (pad-guarded) ----
    #pragma unroll
    for (int p = 0; p < 2; ++p) {
        const int id = tid + p * 512;
        const int row = id >> 3, dc = id & 7;
        u16x8 v8 = {};
        if (tkc0 >= 0) v8 = *(const u16x8*)(kbase + (size_t)(tkc0 + row) * CC + dc * 8);
        *(u16x8*)&kn[row * KP + dc * 8] = v8;
    }
    #pragma unroll
    for (int p = 0; p < 2; ++p) {
        const int id = tid + p * 512;
        const int key = id & 127, dc = id >> 7;
        u16x8 v8 = {};
        if (tkc0 >= 0) v8 = *(const u16x8*)(vbase + (size_t)(tkc0 + key) * CC + dc * 8);
        #pragma unroll
        for (int e = 0; e < 8; ++e) vT[(dc * 8 + e) * VP + key] = v8[e];
    }
    // ---- prefetch chunk 1 into registers (never padded) ----
    u16x8 kr[2], vr[2];
    #pragma unroll
    for (int p = 0; p < 2; ++p) {
        const int id = tid + p * 512;
        kr[p] = *(const u16x8*)(kbase + (size_t)(tkc1 + (id >> 3)) * CC + (id & 7) * 8);
        vr[p] = *(const u16x8*)(vbase + (size_t)(tkc1 + (id & 127)) * CC + (id >> 7) * 8);
    }
    __syncthreads();

    CHUNK(tkc0);
    __syncthreads();            // all chunk-0 reads of kn/vT/Pl complete

    // ---- write chunk 1 from registers ----
    #pragma unroll
    for (int p = 0; p < 2; ++p) {
        const int id = tid + p * 512;
        *(u16x8*)&kn[(id >> 3) * KP + (id & 7) * 8] = kr[p];
    }
    #pragma unroll
    for (int p = 0; p < 2; ++p) {
        const int id = tid + p * 512;
        const int key = id & 127, dc = id >> 7;
        #pragma unroll
        for (int e = 0; e < 8; ++e) vT[(dc * 8 + e) * VP + key] = vr[p][e];
    }
    __syncthreads();

    CHUNK(tkc1);

    // ---- finalize ----
    float inv[4];
    #pragma unroll
    for (int j = 0; j < 4; ++j) {
        l_run[j] += __shfl_xor(l_run[j], 1);
        l_run[j] += __shfl_xor(l_run[j], 2);
        l_run[j] += __shfl_xor(l_run[j], 4);
        l_run[j] += __shfl_xor(l_run[j], 8);
        inv[j] = 1.f / l_run[j];
    }
    u16* obase = o + rowbase * CC + h * 64;
    const int r0 = tq0 + wrow + gr * 4;
    #pragma unroll
    for (int n = 0; n < 4; ++n) {
        const int d = n * 16 + cl;
        #pragma unroll
        for (int j = 0; j < 4; ++j)
            obase[(size_t)(r0 + j) * CC + d] = f2bf(oacc[n][j] * inv[j]);
    }
}

extern "C" void kernel_launch(void* const* d_in, const int* in_sizes, int n_in,
                              void* d_out, int out_size, void* d_ws, size_t ws_size,
                              hipStream_t stream)
{
    (void)in_sizes; (void)n_in; (void)out_size;
    const float* x      = (const float*)d_in[0];   // [4,8192,512] fp32
    const float* w_qkv  = (const float*)d_in[1];   // [1536,512]   fp32
    const float* w_proj = (const float*)d_in[2];   // [512,512]    fp32
    const float* b_proj = (const float*)d_in[3];   // [512]        fp32
    float* out = (float*)d_out;                    // [4,8192,512] fp32

    const int BN = 4 * 8192;                       // 32768 rows
    const size_t qkv_b = (size_t)BN * 1536 * 2;    // 96 MiB
    const size_t xb_b  = (size_t)BN * 512 * 2;     // 32 MiB
    const size_t wq_b  = (size_t)1536 * 512 * 2;
    const size_t wp_b  = (size_t)512 * 512 * 2;

    uint8_t* p = (uint8_t*)d_ws;
    u16* qkv = (u16*)p;

    if (ws_size >= qkv_b + xb_b + wq_b + wp_b) {
        u16* xb  = (u16*)(p + qkv_b);
        u16* wqb = (u16*)(p + qkv_b + xb_b);
        u16* wpb = (u16*)(p + qkv_b + xb_b + wq_b);
        cvt3<<<1088, 256, 0, stream>>>(x, xb, w_qkv, wqb, w_proj, wpb);
        // qkv(bf16) = x @ w_qkv^T  (single-barrier pipeline) + K-norm epilogue
        gemm_pipe<16, false, true><<<dim3(12, 256), 256, 0, stream>>>(
            xb, 512, wqb, 512, nullptr, qkv, 1536);
        attn_kernel<<<dim3(4 * 8 * 64), 512, 0, stream>>>(qkv, qkv);
        // out(fp32) = attnO @ w_proj^T + b_proj  (same pipeline)
        gemm_pipe<16, true, false><<<dim3(4, 256), 256, 0, stream>>>(
            qkv, 1536, wpb, 512, b_proj, out, 512);
    } else {
        // fallback: fp32 register-staged path
        gemm_bt_f32<true, false, true><<<dim3(12, BN / 128), 256, 0, stream>>>(
            x, 512, w_qkv, 512, nullptr, qkv, 1536, 512);
        attn_kernel<<<dim3(4 * 8 * 64), 512, 0, stream>>>(qkv, qkv);
        gemm_bt_f32<false, true, false><<<dim3(4, BN / 128), 256, 0, stream>>>(
            qkv, 1536, w_proj, 512, b_proj, out, 512, 512);
    }
}

// Round 17
// 172.189 us; speedup vs baseline: 1.0540x; 1.0540x over previous
//
#include <hip/hip_runtime.h>
#include <stdint.h>

typedef uint16_t u16;
typedef __bf16 bf16x8 __attribute__((ext_vector_type(8)));
typedef float f32x4 __attribute__((ext_vector_type(4)));
typedef uint16_t u16x4 __attribute__((ext_vector_type(4)));
typedef uint16_t u16x8 __attribute__((ext_vector_type(8)));

typedef __attribute__((address_space(1))) void as1_void;
typedef __attribute__((address_space(3))) void as3_void;

__device__ __forceinline__ float bf2f(u16 b) {
    union { uint32_t u; float f; } v; v.u = ((uint32_t)b) << 16; return v.f;
}
__device__ __forceinline__ u16 f2bf(float f) {
    union { float f; uint32_t u; } v; v.f = f;
    uint32_t u = v.u;
    u += 0x7fffu + ((u >> 16) & 1u);   // RNE
    return (u16)(u >> 16);
}
__device__ __forceinline__ void gload_lds16(const u16* g, u16* l) {
    __builtin_amdgcn_global_load_lds((as1_void*)g, (as3_void*)l, 16, 0, 0);
}

// ---------------------------------------------------------------------------
// Fused fp32->bf16 convert of x, w_qkv, w_proj in one launch (r5-proven).
// ---------------------------------------------------------------------------
__global__ __launch_bounds__(256) void cvt3(
    const float* __restrict__ x,  u16* __restrict__ xb,
    const float* __restrict__ wq, u16* __restrict__ wqb,
    const float* __restrict__ wp, u16* __restrict__ wpb)
{
    const float* src; u16* dst; int base, nb;
    const int b = blockIdx.x;
    if (b < 1024)      { src = x;  dst = xb;  base = b;        nb = 1024; }
    else if (b < 1072) { src = wq; dst = wqb; base = b - 1024; nb = 48;   }
    else               { src = wp; dst = wpb; base = b - 1072; nb = 16;   }
    size_t i = ((size_t)base * 256 + threadIdx.x) * 8;
    const size_t stride = (size_t)nb * 256 * 8;
    #pragma unroll
    for (int it = 0; it < 8; ++it, i += stride) {
        f32x4 a = *(const f32x4*)(src + i);
        f32x4 c = *(const f32x4*)(src + i + 4);
        u16x8 o;
        o[0] = f2bf(a[0]); o[1] = f2bf(a[1]); o[2] = f2bf(a[2]); o[3] = f2bf(a[3]);
        o[4] = f2bf(c[0]); o[5] = f2bf(c[1]); o[6] = f2bf(c[2]); o[7] = f2bf(c[3]);
        *(u16x8*)(dst + i) = o;
    }
}

// ---------------------------------------------------------------------------
// Pipelined bf16 GEMM (r15-verified structure): C = A @ B^T (+bias if BIAS).
// 128x128 tile, BK=32, 4 waves, 4 LDS buffers (64KB -> 2 blocks/CU),
// stage-3-ahead global_load_lds, ONE barrier per K-tile.
// Body(t): STAGE(t+3) | MFMA(t) (operands pre-read) | reads(t+1) |
// lgkmcnt(0) vmcnt(4) barrier. Invariant: barrier_t => S(t+1) landed on all
// waves (each wave's vmcnt(4) leaves only S(t+2) outstanding; 4 loads/STAGE).
// LDS rotation: slot = (chunk + (row>>1)) & 3 -> 2 lanes/bank-group (free).
// BIAS is a template bool so the GEMM1 instantiation compiles bit-identical
// to the r15-measured 79us kernel (rule #19: runtime bias ptr perturbed it).
// ---------------------------------------------------------------------------
template<int NT, bool C_F32, bool NORMK, bool BIAS>   // NT = K/32
__global__ __launch_bounds__(256, 2) void gemm_pipe(
    const u16* __restrict__ A, int lda,
    const u16* __restrict__ B, int ldb,
    const float* __restrict__ bias,
    void* __restrict__ Cv, int ldc)
{
    __shared__ u16 lA[4][128 * 32];   // 8 KB each
    __shared__ u16 lB[4][128 * 32];

    const int tid  = threadIdx.x;
    const int lane = tid & 63;
    const int wave = tid >> 6;
    const int wr = (wave >> 1) * 64;
    const int wc = (wave & 1) * 64;
    const int cl = lane & 15;
    const int gr = lane >> 4;

    // T1: XCD chunked swizzle (grid % 8 == 0)
    int fid = blockIdx.y * gridDim.x + blockIdx.x;
    const int nwg = gridDim.x * gridDim.y;
    fid = (fid & 7) * (nwg >> 3) + (fid >> 3);
    const int row0 = (fid / gridDim.x) * 128;
    const int col0 = (fid % gridDim.x) * 128;

    f32x4 acc[4][4] = {};

    auto STAGE = [&](int t, int d) {   // 2 A + 2 B gload_lds per thread
        const int k0 = t * 32;
        #pragma unroll
        for (int i = 0; i < 2; ++i) {
            const int id  = i * 256 + tid;
            const int row = id >> 2;
            const int sch = ((id & 3) - ((row >> 1) & 3)) & 3;
            gload_lds16(A + (size_t)(row0 + row) * lda + k0 + sch * 8, &lA[d][id * 8]);
            gload_lds16(B + (size_t)(col0 + row) * ldb + k0 + sch * 8, &lB[d][id * 8]);
        }
    };

    bf16x8 af[4], bfv[4];
    auto READS = [&](int t) {
        const u16* la = lA[t & 3];
        const u16* lb = lB[t & 3];
        #pragma unroll
        for (int m = 0; m < 4; ++m) {
            const int ra = wr + m * 16 + cl;
            af[m] = *(const bf16x8*)&la[ra * 32 + ((gr + (ra >> 1)) & 3) * 8];
        }
        #pragma unroll
        for (int n = 0; n < 4; ++n) {
            const int rb = wc + n * 16 + cl;
            bfv[n] = *(const bf16x8*)&lb[rb * 32 + ((gr + (rb >> 1)) & 3) * 8];
        }
    };

    // prologue
    STAGE(0, 0); STAGE(1, 1); STAGE(2, 2);
    asm volatile("s_waitcnt vmcnt(4)" ::: "memory");   // S0,S1 landed (S2 may fly)
    __builtin_amdgcn_s_barrier();                      // all waves: S0,S1 visible
    READS(0);

    #pragma unroll
    for (int t = 0; t < NT; ++t) {
        if (t + 3 < NT) STAGE(t + 3, (t + 3) & 3);
        __builtin_amdgcn_s_setprio(1);
        #pragma unroll
        for (int m = 0; m < 4; ++m)
            #pragma unroll
            for (int n = 0; n < 4; ++n)
                acc[m][n] = __builtin_amdgcn_mfma_f32_16x16x32_bf16(af[m], bfv[n], acc[m][n], 0, 0, 0);
        __builtin_amdgcn_s_setprio(0);
        if (t + 1 < NT) READS(t + 1);                  // overlaps MFMA(t) pipe
        if (t < NT - 1) {
            asm volatile("s_waitcnt lgkmcnt(0)" ::: "memory");   // my reads captured
            if (t + 3 < NT) asm volatile("s_waitcnt vmcnt(4)" ::: "memory");  // S(t+2) landed
            else            asm volatile("s_waitcnt vmcnt(0)" ::: "memory");  // tail drain
            __builtin_amdgcn_s_barrier();
        }
    }

    if constexpr (NORMK) {
        if (col0 + wc >= 512 && col0 + wc < 1024) {
            #pragma unroll
            for (int m = 0; m < 4; ++m)
                #pragma unroll
                for (int j = 0; j < 4; ++j) {
                    float ss = 0.f;
                    #pragma unroll
                    for (int n = 0; n < 4; ++n) ss += acc[m][n][j] * acc[m][n][j];
                    ss += __shfl_xor(ss, 1);
                    ss += __shfl_xor(ss, 2);
                    ss += __shfl_xor(ss, 4);
                    ss += __shfl_xor(ss, 8);
                    const float scl = 1.f / fmaxf(sqrtf(ss), 1e-12f);
                    #pragma unroll
                    for (int n = 0; n < 4; ++n) acc[m][n][j] *= scl;
                }
        }
    }

    #pragma unroll
    for (int m = 0; m < 4; ++m) {
        const int r = row0 + wr + m * 16 + gr * 4;
        #pragma unroll
        for (int n = 0; n < 4; ++n) {
            const int c = col0 + wc + n * 16 + cl;
            float bv = 0.f;
            if constexpr (BIAS) bv = bias[c];
            #pragma unroll
            for (int j = 0; j < 4; ++j) {
                const float val = acc[m][n][j] + bv;
                if constexpr (C_F32) ((float*)Cv)[(size_t)(r + j) * ldc + c] = val;
                else                 ((u16*)Cv)[(size_t)(r + j) * ldc + c] = f2bf(val);
            }
        }
    }
}

// ---------------------------------------------------------------------------
// fp32-input fallback GEMM (register staging + convert). Used only if ws too small.
// ---------------------------------------------------------------------------
template<bool A_F32, bool C_F32, bool NORMK>
__global__ __launch_bounds__(256) void gemm_bt_f32(
    const void* __restrict__ Av, int lda,
    const float* __restrict__ B, int ldb,
    const float* __restrict__ bias,
    void* __restrict__ Cv, int ldc,
    int K)
{
    __shared__ u16 lA[128 * 32];
    __shared__ u16 lB[128 * 32];

    const int tid  = threadIdx.x;
    const int lane = tid & 63;
    const int wave = tid >> 6;
    const int wr   = (wave >> 1) * 64;
    const int wc   = (wave & 1) * 64;
    const int row0 = blockIdx.y * 128;
    const int col0 = blockIdx.x * 128;

    f32x4 acc[4][4] = {};

    for (int k0 = 0; k0 < K; k0 += 32) {
        #pragma unroll
        for (int i = 0; i < 4; ++i) {
            const int idx = i * 256 + tid;
            const int r = idx >> 3;
            const int p = (idx & 7) * 4;
            u16x4 a4, b4;
            if constexpr (A_F32) {
                const float* Af = (const float*)Av;
                f32x4 va = *(const f32x4*)(Af + (size_t)(row0 + r) * lda + k0 + p);
                a4[0] = f2bf(va[0]); a4[1] = f2bf(va[1]); a4[2] = f2bf(va[2]); a4[3] = f2bf(va[3]);
            } else {
                const u16* Ab = (const u16*)Av;
                a4 = *(const u16x4*)(Ab + (size_t)(row0 + r) * lda + k0 + p);
            }
            {
                f32x4 vb = *(const f32x4*)(B + (size_t)(col0 + r) * ldb + k0 + p);
                b4[0] = f2bf(vb[0]); b4[1] = f2bf(vb[1]); b4[2] = f2bf(vb[2]); b4[3] = f2bf(vb[3]);
            }
            *(u16x4*)&lA[r * 32 + p] = a4;
            *(u16x4*)&lB[r * 32 + p] = b4;
        }
        __syncthreads();

        bf16x8 af[4], bfv[4];
        #pragma unroll
        for (int m = 0; m < 4; ++m)
            af[m] = *(const bf16x8*)(lA + (wr + m * 16 + (lane & 15)) * 32 + (lane >> 4) * 8);
        #pragma unroll
        for (int n = 0; n < 4; ++n)
            bfv[n] = *(const bf16x8*)(lB + (wc + n * 16 + (lane & 15)) * 32 + (lane >> 4) * 8);
        #pragma unroll
        for (int m = 0; m < 4; ++m)
            #pragma unroll
            for (int n = 0; n < 4; ++n)
                acc[m][n] = __builtin_amdgcn_mfma_f32_16x16x32_bf16(af[m], bfv[n], acc[m][n], 0, 0, 0);
        __syncthreads();
    }

    if constexpr (NORMK) {
        if (col0 >= 512 && col0 < 1024) {
            #pragma unroll
            for (int m = 0; m < 4; ++m)
                #pragma unroll
                for (int j = 0; j < 4; ++j) {
                    float ss = 0.f;
                    #pragma unroll
                    for (int n = 0; n < 4; ++n) ss += acc[m][n][j] * acc[m][n][j];
                    ss += __shfl_xor(ss, 1);
                    ss += __shfl_xor(ss, 2);
                    ss += __shfl_xor(ss, 4);
                    ss += __shfl_xor(ss, 8);
                    const float scl = 1.f / fmaxf(sqrtf(ss), 1e-12f);
                    #pragma unroll
                    for (int n = 0; n < 4; ++n) acc[m][n][j] *= scl;
                }
        }
    }

    #pragma unroll
    for (int m = 0; m < 4; ++m) {
        const int r = row0 + wr + m * 16 + ((lane >> 4) << 2);
        #pragma unroll
        for (int n = 0; n < 4; ++n) {
            const int c = col0 + wc + n * 16 + (lane & 15);
            const float bv = bias ? bias[c] : 0.f;
            #pragma unroll
            for (int j = 0; j < 4; ++j) {
                const float val = acc[m][n][j] + bv;
                if constexpr (C_F32) ((float*)Cv)[(size_t)(r + j) * ldc + c] = val;
                else                 ((u16*)Cv)[(size_t)(r + j) * ldc + c] = f2bf(val);
            }
        }
    }
}

// ---------------------------------------------------------------------------
// Local attention, online-softmax over two 128-key chunks. Chunk 1's K/V are
// PREFETCHED INTO REGISTERS during chunk-0 staging (chunk 1 is never padded:
// tkc1 = tq0 >= 0) and written to LDS after chunk-0's post-PV barrier (T14).
// ---------------------------------------------------------------------------
__global__ __launch_bounds__(512, 4) void attn_kernel(const u16* qkv, u16* o)
{
    constexpr int CC = 1536;
    constexpr int NTOK = 8192;
    constexpr int KP = 72;
    constexpr int VP = 136;
    constexpr int PP = 136;
    __shared__ u16 kn[128 * KP];
    __shared__ u16 vT[64 * VP];
    __shared__ u16 Pl[128 * PP];

    const int tid  = threadIdx.x;
    const int lane = tid & 63;
    const int wave = tid >> 6;
    const int cl = lane & 15;
    const int gr = lane >> 4;

    int blk = blockIdx.x;
    blk = (blk & 7) * (gridDim.x >> 3) + (blk >> 3);

    const int iw  = blk & 63;
    const int h   = (blk >> 6) & 7;
    const int b   = blk >> 9;

    const int tq0 = iw * 128;
    const int tkc0 = tq0 - 128;
    const int tkc1 = tq0;
    const size_t rowbase = (size_t)b * NTOK;
    const u16* qbase = qkv + rowbase * CC + h * 64;
    const u16* kbase = qbase + 512;
    const u16* vbase = qbase + 1024;

    const int wrow = wave * 16;
    bf16x8 qf[2];
    #pragma unroll
    for (int kk = 0; kk < 2; ++kk)
        qf[kk] = *(const bf16x8*)(qbase + (size_t)(tq0 + wrow + cl) * CC + kk * 32 + gr * 8);

    f32x4 oacc[4] = {};
    float m_run[4] = {-3.0e38f, -3.0e38f, -3.0e38f, -3.0e38f};
    float l_run[4] = {0.f, 0.f, 0.f, 0.f};

    auto CHUNK = [&](int tkc) {
        f32x4 s[8] = {};
        #pragma unroll
        for (int n = 0; n < 8; ++n)
            #pragma unroll
            for (int kk = 0; kk < 2; ++kk) {
                const bf16x8 kf = *(const bf16x8*)&kn[(n * 16 + cl) * KP + kk * 32 + gr * 8];
                s[n] = __builtin_amdgcn_mfma_f32_16x16x32_bf16(qf[kk], kf, s[n], 0, 0, 0);
            }
        float pmax[4] = {-3.0e38f, -3.0e38f, -3.0e38f, -3.0e38f};
        #pragma unroll
        for (int n = 0; n < 8; ++n) {
            const int tkk = tkc + n * 16 + cl;
            const bool pad = tkk < 0;
            #pragma unroll
            for (int j = 0; j < 4; ++j) {
                const int tq = tq0 + wrow + gr * 4 + j;
                float sv = s[n][j] * 0.125f;
                const int rel = tkk - tq;
                sv = (rel == 0) ? -5.0e4f : sv;
                sv = (rel > 0 || pad) ? -6.0e4f : sv;
                s[n][j] = sv;
                pmax[j] = fmaxf(pmax[j], sv);
            }
        }
        float cold[4];
        #pragma unroll
        for (int j = 0; j < 4; ++j) {
            pmax[j] = fmaxf(pmax[j], __shfl_xor(pmax[j], 1));
            pmax[j] = fmaxf(pmax[j], __shfl_xor(pmax[j], 2));
            pmax[j] = fmaxf(pmax[j], __shfl_xor(pmax[j], 4));
            pmax[j] = fmaxf(pmax[j], __shfl_xor(pmax[j], 8));
            const float mn = fmaxf(m_run[j], pmax[j]);
            cold[j] = __expf(m_run[j] - mn);
            m_run[j] = mn;
            l_run[j] *= cold[j];
        }
        #pragma unroll
        for (int n = 0; n < 8; ++n)
            #pragma unroll
            for (int j = 0; j < 4; ++j) {
                const float p = __expf(s[n][j] - m_run[j]);
                s[n][j] = p;
                l_run[j] += p;
            }
        #pragma unroll
        for (int n = 0; n < 4; ++n) {
            f32x4 t = oacc[n];
            t[0] *= cold[0]; t[1] *= cold[1]; t[2] *= cold[2]; t[3] *= cold[3];
            oacc[n] = t;
        }
        #pragma unroll
        for (int n = 0; n < 8; ++n)
            #pragma unroll
            for (int j = 0; j < 4; ++j)
                Pl[(wrow + gr * 4 + j) * PP + n * 16 + cl] = f2bf(s[n][j]);
        __syncthreads();
        #pragma unroll
        for (int kk = 0; kk < 4; ++kk) {
            const bf16x8 pa = *(const bf16x8*)&Pl[(wrow + cl) * PP + kk * 32 + gr * 8];
            #pragma unroll
            for (int n = 0; n < 4; ++n) {
                const bf16x8 vb = *(const bf16x8*)&vT[(n * 16 + cl) * VP + kk * 32 + gr * 8];
                oacc[n] = __builtin_amdgcn_mfma_f32_16x16x32_bf16(pa, vb, oacc[n], 0, 0, 0);
            }
        }
    };

    // ---- stage chunk 0 (pad-guarded) ----
    #pragma unroll
    for (int p = 0; p < 2; ++p) {
        const int id = tid + p * 512;
        const int row = id >> 3, dc = id & 7;
        u16x8 v8 = {};
        if (tkc0 >= 0) v8 = *(const u16x8*)(kbase + (size_t)(tkc0 + row) * CC + dc * 8);
        *(u16x8*)&kn[row * KP + dc * 8] = v8;
    }
    #pragma unroll
    for (int p = 0; p < 2; ++p) {
        const int id = tid + p * 512;
        const int key = id & 127, dc = id >> 7;
        u16x8 v8 = {};
        if (tkc0 >= 0) v8 = *(const u16x8*)(vbase + (size_t)(tkc0 + key) * CC + dc * 8);
        #pragma unroll
        for (int e = 0; e < 8; ++e) vT[(dc * 8 + e) * VP + key] = v8[e];
    }
    // ---- prefetch chunk 1 into registers (never padded) ----
    u16x8 kr[2], vr[2];
    #pragma unroll
    for (int p = 0; p < 2; ++p) {
        const int id = tid + p * 512;
        kr[p] = *(const u16x8*)(kbase + (size_t)(tkc1 + (id >> 3)) * CC + (id & 7) * 8);
        vr[p] = *(const u16x8*)(vbase + (size_t)(tkc1 + (id & 127)) * CC + (id >> 7) * 8);
    }
    __syncthreads();

    CHUNK(tkc0);
    __syncthreads();            // all chunk-0 reads of kn/vT/Pl complete

    // ---- write chunk 1 from registers ----
    #pragma unroll
    for (int p = 0; p < 2; ++p) {
        const int id = tid + p * 512;
        *(u16x8*)&kn[(id >> 3) * KP + (id & 7) * 8] = kr[p];
    }
    #pragma unroll
    for (int p = 0; p < 2; ++p) {
        const int id = tid + p * 512;
        const int key = id & 127, dc = id >> 7;
        #pragma unroll
        for (int e = 0; e < 8; ++e) vT[(dc * 8 + e) * VP + key] = vr[p][e];
    }
    __syncthreads();

    CHUNK(tkc1);

    // ---- finalize ----
    float inv[4];
    #pragma unroll
    for (int j = 0; j < 4; ++j) {
        l_run[j] += __shfl_xor(l_run[j], 1);
        l_run[j] += __shfl_xor(l_run[j], 2);
        l_run[j] += __shfl_xor(l_run[j], 4);
        l_run[j] += __shfl_xor(l_run[j], 8);
        inv[j] = 1.f / l_run[j];
    }
    u16* obase = o + rowbase * CC + h * 64;
    const int r0 = tq0 + wrow + gr * 4;
    #pragma unroll
    for (int n = 0; n < 4; ++n) {
        const int d = n * 16 + cl;
        #pragma unroll
        for (int j = 0; j < 4; ++j)
            obase[(size_t)(r0 + j) * CC + d] = f2bf(oacc[n][j] * inv[j]);
    }
}

extern "C" void kernel_launch(void* const* d_in, const int* in_sizes, int n_in,
                              void* d_out, int out_size, void* d_ws, size_t ws_size,
                              hipStream_t stream)
{
    (void)in_sizes; (void)n_in; (void)out_size;
    const float* x      = (const float*)d_in[0];   // [4,8192,512] fp32
    const float* w_qkv  = (const float*)d_in[1];   // [1536,512]   fp32
    const float* w_proj = (const float*)d_in[2];   // [512,512]    fp32
    const float* b_proj = (const float*)d_in[3];   // [512]        fp32
    float* out = (float*)d_out;                    // [4,8192,512] fp32

    const int BN = 4 * 8192;                       // 32768 rows
    const size_t qkv_b = (size_t)BN * 1536 * 2;    // 96 MiB
    const size_t xb_b  = (size_t)BN * 512 * 2;     // 32 MiB
    const size_t wq_b  = (size_t)1536 * 512 * 2;
    const size_t wp_b  = (size_t)512 * 512 * 2;

    uint8_t* p = (uint8_t*)d_ws;
    u16* qkv = (u16*)p;

    if (ws_size >= qkv_b + xb_b + wq_b + wp_b) {
        u16* xb  = (u16*)(p + qkv_b);
        u16* wqb = (u16*)(p + qkv_b + xb_b);
        u16* wpb = (u16*)(p + qkv_b + xb_b + wq_b);
        cvt3<<<1088, 256, 0, stream>>>(x, xb, w_qkv, wqb, w_proj, wpb);
        // qkv(bf16) = x @ w_qkv^T  (single-barrier pipeline) + K-norm epilogue
        gemm_pipe<16, false, true, false><<<dim3(12, 256), 256, 0, stream>>>(
            xb, 512, wqb, 512, nullptr, qkv, 1536);
        attn_kernel<<<dim3(4 * 8 * 64), 512, 0, stream>>>(qkv, qkv);
        // out(fp32) = attnO @ w_proj^T + b_proj  (same pipeline, BIAS variant)
        gemm_pipe<16, true, false, true><<<dim3(4, 256), 256, 0, stream>>>(
            qkv, 1536, wpb, 512, b_proj, out, 512);
    } else {
        // fallback: fp32 register-staged path
        gemm_bt_f32<true, false, true><<<dim3(12, BN / 128), 256, 0, stream>>>(
            x, 512, w_qkv, 512, nullptr, qkv, 1536, 512);
        attn_kernel<<<dim3(4 * 8 * 64), 512, 0, stream>>>(qkv, qkv);
        gemm_bt_f32<false, true, false><<<dim3(4, BN / 128), 256, 0, stream>>>(
            qkv, 1536, w_proj, 512, b_proj, out, 512, 512);
    }
}

// Round 18
// 166.172 us; speedup vs baseline: 1.0922x; 1.0362x over previous
//
#include <hip/hip_runtime.h>
#include <stdint.h>

typedef uint16_t u16;
typedef __bf16 bf16x8 __attribute__((ext_vector_type(8)));
typedef float f32x4 __attribute__((ext_vector_type(4)));
typedef uint16_t u16x4 __attribute__((ext_vector_type(4)));
typedef uint16_t u16x8 __attribute__((ext_vector_type(8)));

typedef __attribute__((address_space(1))) void as1_void;
typedef __attribute__((address_space(3))) void as3_void;

__device__ __forceinline__ float bf2f(u16 b) {
    union { uint32_t u; float f; } v; v.u = ((uint32_t)b) << 16; return v.f;
}
__device__ __forceinline__ u16 f2bf(float f) {
    union { float f; uint32_t u; } v; v.f = f;
    uint32_t u = v.u;
    u += 0x7fffu + ((u >> 16) & 1u);   // RNE
    return (u16)(u >> 16);
}
__device__ __forceinline__ void gload_lds16(const u16* g, u16* l) {
    __builtin_amdgcn_global_load_lds((as1_void*)g, (as3_void*)l, 16, 0, 0);
}

// ---------------------------------------------------------------------------
// Fused fp32->bf16 convert of x, w_qkv, w_proj in one launch (r5-proven).
// ---------------------------------------------------------------------------
__global__ __launch_bounds__(256) void cvt3(
    const float* __restrict__ x,  u16* __restrict__ xb,
    const float* __restrict__ wq, u16* __restrict__ wqb,
    const float* __restrict__ wp, u16* __restrict__ wpb)
{
    const float* src; u16* dst; int base, nb;
    const int b = blockIdx.x;
    if (b < 1024)      { src = x;  dst = xb;  base = b;        nb = 1024; }
    else if (b < 1072) { src = wq; dst = wqb; base = b - 1024; nb = 48;   }
    else               { src = wp; dst = wpb; base = b - 1072; nb = 16;   }
    size_t i = ((size_t)base * 256 + threadIdx.x) * 8;
    const size_t stride = (size_t)nb * 256 * 8;
    #pragma unroll
    for (int it = 0; it < 8; ++it, i += stride) {
        f32x4 a = *(const f32x4*)(src + i);
        f32x4 c = *(const f32x4*)(src + i + 4);
        u16x8 o;
        o[0] = f2bf(a[0]); o[1] = f2bf(a[1]); o[2] = f2bf(a[2]); o[3] = f2bf(a[3]);
        o[4] = f2bf(c[0]); o[5] = f2bf(c[1]); o[6] = f2bf(c[2]); o[7] = f2bf(c[3]);
        *(u16x8*)(dst + i) = o;
    }
}

// ---------------------------------------------------------------------------
// Pipelined bf16 GEMM, 256x256 tile (r15-verified single-barrier schedule,
// scaled up): C = A @ B^T (+bias if BIAS). BK=32, 8 waves (2M x 4N),
// 4 LDS buffers of [256][32] bf16 for A and B (128 KB -> 1 block/CU),
// stage-3-ahead global_load_lds (4 loads/thread/STAGE -> SAME vmcnt schedule
// as the verified 128^2 kernel). Body(t): STAGE(t+3) | MFMA(t) | READS(t+1) |
// lgkmcnt(0) vmcnt(4) barrier. Invariant: barrier(t) => S(t+2) landed
// (vmcnt(4) leaves only S(t+3) outstanding), so READS(t+1) in body t+1 is
// safe; buffer (t+3)&3 was fully read two barriers earlier.
// 256^2 halves LDS bytes per output vs 128^2 (A read 4x, B 2x, 4x outputs):
// LDS total ~20us ~= MFMA 20.7us -> balanced.
// Rotation swizzle: slot=(chunk+(row>>1))&3 (re-audited: 8 distinct bank
// granules over each 16-lane read group, 2 lanes each = conflict-free).
// ---------------------------------------------------------------------------
template<int NT, bool C_F32, bool NORMK, bool BIAS>   // NT = K/32
__global__ __launch_bounds__(512, 2) void gemm_pipe256(
    const u16* __restrict__ A, int lda,
    const u16* __restrict__ B, int ldb,
    const float* __restrict__ bias,
    void* __restrict__ Cv, int ldc)
{
    __shared__ u16 lA[4][256 * 32];   // 16 KB each
    __shared__ u16 lB[4][256 * 32];

    const int tid  = threadIdx.x;
    const int lane = tid & 63;
    const int wave = tid >> 6;
    const int wm = wave >> 2;          // 0..1 (M half: 128 rows)
    const int wn = wave & 3;           // 0..3 (N quarter: 64 cols)
    const int cl = lane & 15;
    const int gr = lane >> 4;

    // T1: XCD chunked swizzle (grid % 8 == 0)
    int fid = blockIdx.y * gridDim.x + blockIdx.x;
    const int nwg = gridDim.x * gridDim.y;
    fid = (fid & 7) * (nwg >> 3) + (fid >> 3);
    const int row0 = (fid / gridDim.x) * 256;
    const int col0 = (fid % gridDim.x) * 256;

    f32x4 acc[8][4] = {};

    auto STAGE = [&](int t, int d) {   // 2 A + 2 B gload_lds per thread
        const int k0 = t * 32;
        #pragma unroll
        for (int i = 0; i < 2; ++i) {
            const int id  = i * 512 + tid;           // 1024 chunks of 16B
            const int row = id >> 2;
            const int sch = ((id & 3) - ((row >> 1) & 3)) & 3;
            gload_lds16(A + (size_t)(row0 + row) * lda + k0 + sch * 8, &lA[d][id * 8]);
            gload_lds16(B + (size_t)(col0 + row) * ldb + k0 + sch * 8, &lB[d][id * 8]);
        }
    };

    bf16x8 af[8], bfv[4];
    auto READS = [&](int t) {
        const u16* la = lA[t & 3];
        const u16* lb = lB[t & 3];
        #pragma unroll
        for (int m = 0; m < 8; ++m) {
            const int ra = wm * 128 + m * 16 + cl;
            af[m] = *(const bf16x8*)&la[ra * 32 + ((gr + (ra >> 1)) & 3) * 8];
        }
        #pragma unroll
        for (int n = 0; n < 4; ++n) {
            const int rb = wn * 64 + n * 16 + cl;
            bfv[n] = *(const bf16x8*)&lb[rb * 32 + ((gr + (rb >> 1)) & 3) * 8];
        }
    };

    // prologue
    STAGE(0, 0); STAGE(1, 1); STAGE(2, 2);
    asm volatile("s_waitcnt vmcnt(4)" ::: "memory");   // S0,S1 landed (S2 may fly)
    __builtin_amdgcn_s_barrier();                      // all waves: S0,S1 visible
    READS(0);

    #pragma unroll
    for (int t = 0; t < NT; ++t) {
        if (t + 3 < NT) STAGE(t + 3, (t + 3) & 3);
        __builtin_amdgcn_s_setprio(1);
        #pragma unroll
        for (int m = 0; m < 8; ++m)
            #pragma unroll
            for (int n = 0; n < 4; ++n)
                acc[m][n] = __builtin_amdgcn_mfma_f32_16x16x32_bf16(af[m], bfv[n], acc[m][n], 0, 0, 0);
        __builtin_amdgcn_s_setprio(0);
        if (t + 1 < NT) READS(t + 1);                  // overlaps MFMA(t) pipe
        if (t < NT - 1) {
            asm volatile("s_waitcnt lgkmcnt(0)" ::: "memory");   // my reads captured
            if (t + 3 < NT) asm volatile("s_waitcnt vmcnt(4)" ::: "memory");  // S(t+2) landed
            else            asm volatile("s_waitcnt vmcnt(0)" ::: "memory");  // tail drain
            __builtin_amdgcn_s_barrier();
        }
    }

    if constexpr (NORMK) {
        if (col0 + wn * 64 >= 512 && col0 + wn * 64 < 1024) {
            #pragma unroll
            for (int m = 0; m < 8; ++m)
                #pragma unroll
                for (int j = 0; j < 4; ++j) {
                    float ss = 0.f;
                    #pragma unroll
                    for (int n = 0; n < 4; ++n) ss += acc[m][n][j] * acc[m][n][j];
                    ss += __shfl_xor(ss, 1);
                    ss += __shfl_xor(ss, 2);
                    ss += __shfl_xor(ss, 4);
                    ss += __shfl_xor(ss, 8);
                    const float scl = 1.f / fmaxf(sqrtf(ss), 1e-12f);
                    #pragma unroll
                    for (int n = 0; n < 4; ++n) acc[m][n][j] *= scl;
                }
        }
    }

    #pragma unroll
    for (int m = 0; m < 8; ++m) {
        const int r = row0 + wm * 128 + m * 16 + gr * 4;
        #pragma unroll
        for (int n = 0; n < 4; ++n) {
            const int c = col0 + wn * 64 + n * 16 + cl;
            float bv = 0.f;
            if constexpr (BIAS) bv = bias[c];
            #pragma unroll
            for (int j = 0; j < 4; ++j) {
                const float val = acc[m][n][j] + bv;
                if constexpr (C_F32) ((float*)Cv)[(size_t)(r + j) * ldc + c] = val;
                else                 ((u16*)Cv)[(size_t)(r + j) * ldc + c] = f2bf(val);
            }
        }
    }
}

// ---------------------------------------------------------------------------
// fp32-input fallback GEMM (register staging + convert). Used only if ws too small.
// ---------------------------------------------------------------------------
template<bool A_F32, bool C_F32, bool NORMK>
__global__ __launch_bounds__(256) void gemm_bt_f32(
    const void* __restrict__ Av, int lda,
    const float* __restrict__ B, int ldb,
    const float* __restrict__ bias,
    void* __restrict__ Cv, int ldc,
    int K)
{
    __shared__ u16 lA[128 * 32];
    __shared__ u16 lB[128 * 32];

    const int tid  = threadIdx.x;
    const int lane = tid & 63;
    const int wave = tid >> 6;
    const int wr   = (wave >> 1) * 64;
    const int wc   = (wave & 1) * 64;
    const int row0 = blockIdx.y * 128;
    const int col0 = blockIdx.x * 128;

    f32x4 acc[4][4] = {};

    for (int k0 = 0; k0 < K; k0 += 32) {
        #pragma unroll
        for (int i = 0; i < 4; ++i) {
            const int idx = i * 256 + tid;
            const int r = idx >> 3;
            const int p = (idx & 7) * 4;
            u16x4 a4, b4;
            if constexpr (A_F32) {
                const float* Af = (const float*)Av;
                f32x4 va = *(const f32x4*)(Af + (size_t)(row0 + r) * lda + k0 + p);
                a4[0] = f2bf(va[0]); a4[1] = f2bf(va[1]); a4[2] = f2bf(va[2]); a4[3] = f2bf(va[3]);
            } else {
                const u16* Ab = (const u16*)Av;
                a4 = *(const u16x4*)(Ab + (size_t)(row0 + r) * lda + k0 + p);
            }
            {
                f32x4 vb = *(const f32x4*)(B + (size_t)(col0 + r) * ldb + k0 + p);
                b4[0] = f2bf(vb[0]); b4[1] = f2bf(vb[1]); b4[2] = f2bf(vb[2]); b4[3] = f2bf(vb[3]);
            }
            *(u16x4*)&lA[r * 32 + p] = a4;
            *(u16x4*)&lB[r * 32 + p] = b4;
        }
        __syncthreads();

        bf16x8 af[4], bfv[4];
        #pragma unroll
        for (int m = 0; m < 4; ++m)
            af[m] = *(const bf16x8*)(lA + (wr + m * 16 + (lane & 15)) * 32 + (lane >> 4) * 8);
        #pragma unroll
        for (int n = 0; n < 4; ++n)
            bfv[n] = *(const bf16x8*)(lB + (wc + n * 16 + (lane & 15)) * 32 + (lane >> 4) * 8);
        #pragma unroll
        for (int m = 0; m < 4; ++m)
            #pragma unroll
            for (int n = 0; n < 4; ++n)
                acc[m][n] = __builtin_amdgcn_mfma_f32_16x16x32_bf16(af[m], bfv[n], acc[m][n], 0, 0, 0);
        __syncthreads();
    }

    if constexpr (NORMK) {
        if (col0 >= 512 && col0 < 1024) {
            #pragma unroll
            for (int m = 0; m < 4; ++m)
                #pragma unroll
                for (int j = 0; j < 4; ++j) {
                    float ss = 0.f;
                    #pragma unroll
                    for (int n = 0; n < 4; ++n) ss += acc[m][n][j] * acc[m][n][j];
                    ss += __shfl_xor(ss, 1);
                    ss += __shfl_xor(ss, 2);
                    ss += __shfl_xor(ss, 4);
                    ss += __shfl_xor(ss, 8);
                    const float scl = 1.f / fmaxf(sqrtf(ss), 1e-12f);
                    #pragma unroll
                    for (int n = 0; n < 4; ++n) acc[m][n][j] *= scl;
                }
        }
    }

    #pragma unroll
    for (int m = 0; m < 4; ++m) {
        const int r = row0 + wr + m * 16 + ((lane >> 4) << 2);
        #pragma unroll
        for (int n = 0; n < 4; ++n) {
            const int c = col0 + wc + n * 16 + (lane & 15);
            const float bv = bias ? bias[c] : 0.f;
            #pragma unroll
            for (int j = 0; j < 4; ++j) {
                const float val = acc[m][n][j] + bv;
                if constexpr (C_F32) ((float*)Cv)[(size_t)(r + j) * ldc + c] = val;
                else                 ((u16*)Cv)[(size_t)(r + j) * ldc + c] = f2bf(val);
            }
        }
    }
}

// ---------------------------------------------------------------------------
// Local attention, online-softmax over two 128-key chunks. Chunk 1's K/V are
// PREFETCHED INTO REGISTERS during chunk-0 staging (chunk 1 is never padded:
// tkc1 = tq0 >= 0) and written to LDS after chunk-0's post-PV barrier (T14).
// ---------------------------------------------------------------------------
__global__ __launch_bounds__(512, 4) void attn_kernel(const u16* qkv, u16* o)
{
    constexpr int CC = 1536;
    constexpr int NTOK = 8192;
    constexpr int KP = 72;
    constexpr int VP = 136;
    constexpr int PP = 136;
    __shared__ u16 kn[128 * KP];
    __shared__ u16 vT[64 * VP];
    __shared__ u16 Pl[128 * PP];

    const int tid  = threadIdx.x;
    const int lane = tid & 63;
    const int wave = tid >> 6;
    const int cl = lane & 15;
    const int gr = lane >> 4;

    int blk = blockIdx.x;
    blk = (blk & 7) * (gridDim.x >> 3) + (blk >> 3);

    const int iw  = blk & 63;
    const int h   = (blk >> 6) & 7;
    const int b   = blk >> 9;

    const int tq0 = iw * 128;
    const int tkc0 = tq0 - 128;
    const int tkc1 = tq0;
    const size_t rowbase = (size_t)b * NTOK;
    const u16* qbase = qkv + rowbase * CC + h * 64;
    const u16* kbase = qbase + 512;
    const u16* vbase = qbase + 1024;

    const int wrow = wave * 16;
    bf16x8 qf[2];
    #pragma unroll
    for (int kk = 0; kk < 2; ++kk)
        qf[kk] = *(const bf16x8*)(qbase + (size_t)(tq0 + wrow + cl) * CC + kk * 32 + gr * 8);

    f32x4 oacc[4] = {};
    float m_run[4] = {-3.0e38f, -3.0e38f, -3.0e38f, -3.0e38f};
    float l_run[4] = {0.f, 0.f, 0.f, 0.f};

    auto CHUNK = [&](int tkc) {
        f32x4 s[8] = {};
        #pragma unroll
        for (int n = 0; n < 8; ++n)
            #pragma unroll
            for (int kk = 0; kk < 2; ++kk) {
                const bf16x8 kf = *(const bf16x8*)&kn[(n * 16 + cl) * KP + kk * 32 + gr * 8];
                s[n] = __builtin_amdgcn_mfma_f32_16x16x32_bf16(qf[kk], kf, s[n], 0, 0, 0);
            }
        float pmax[4] = {-3.0e38f, -3.0e38f, -3.0e38f, -3.0e38f};
        #pragma unroll
        for (int n = 0; n < 8; ++n) {
            const int tkk = tkc + n * 16 + cl;
            const bool pad = tkk < 0;
            #pragma unroll
            for (int j = 0; j < 4; ++j) {
                const int tq = tq0 + wrow + gr * 4 + j;
                float sv = s[n][j] * 0.125f;
                const int rel = tkk - tq;
                sv = (rel == 0) ? -5.0e4f : sv;
                sv = (rel > 0 || pad) ? -6.0e4f : sv;
                s[n][j] = sv;
                pmax[j] = fmaxf(pmax[j], sv);
            }
        }
        float cold[4];
        #pragma unroll
        for (int j = 0; j < 4; ++j) {
            pmax[j] = fmaxf(pmax[j], __shfl_xor(pmax[j], 1));
            pmax[j] = fmaxf(pmax[j], __shfl_xor(pmax[j], 2));
            pmax[j] = fmaxf(pmax[j], __shfl_xor(pmax[j], 4));
            pmax[j] = fmaxf(pmax[j], __shfl_xor(pmax[j], 8));
            const float mn = fmaxf(m_run[j], pmax[j]);
            cold[j] = __expf(m_run[j] - mn);
            m_run[j] = mn;
            l_run[j] *= cold[j];
        }
        #pragma unroll
        for (int n = 0; n < 8; ++n)
            #pragma unroll
            for (int j = 0; j < 4; ++j) {
                const float p = __expf(s[n][j] - m_run[j]);
                s[n][j] = p;
                l_run[j] += p;
            }
        #pragma unroll
        for (int n = 0; n < 4; ++n) {
            f32x4 t = oacc[n];
            t[0] *= cold[0]; t[1] *= cold[1]; t[2] *= cold[2]; t[3] *= cold[3];
            oacc[n] = t;
        }
        #pragma unroll
        for (int n = 0; n < 8; ++n)
            #pragma unroll
            for (int j = 0; j < 4; ++j)
                Pl[(wrow + gr * 4 + j) * PP + n * 16 + cl] = f2bf(s[n][j]);
        __syncthreads();
        #pragma unroll
        for (int kk = 0; kk < 4; ++kk) {
            const bf16x8 pa = *(const bf16x8*)&Pl[(wrow + cl) * PP + kk * 32 + gr * 8];
            #pragma unroll
            for (int n = 0; n < 4; ++n) {
                const bf16x8 vb = *(const bf16x8*)&vT[(n * 16 + cl) * VP + kk * 32 + gr * 8];
                oacc[n] = __builtin_amdgcn_mfma_f32_16x16x32_bf16(pa, vb, oacc[n], 0, 0, 0);
            }
        }
    };

    // ---- stage chunk 0 (pad-guarded) ----
    #pragma unroll
    for (int p = 0; p < 2; ++p) {
        const int id = tid + p * 512;
        const int row = id >> 3, dc = id & 7;
        u16x8 v8 = {};
        if (tkc0 >= 0) v8 = *(const u16x8*)(kbase + (size_t)(tkc0 + row) * CC + dc * 8);
        *(u16x8*)&kn[row * KP + dc * 8] = v8;
    }
    #pragma unroll
    for (int p = 0; p < 2; ++p) {
        const int id = tid + p * 512;
        const int key = id & 127, dc = id >> 7;
        u16x8 v8 = {};
        if (tkc0 >= 0) v8 = *(const u16x8*)(vbase + (size_t)(tkc0 + key) * CC + dc * 8);
        #pragma unroll
        for (int e = 0; e < 8; ++e) vT[(dc * 8 + e) * VP + key] = v8[e];
    }
    // ---- prefetch chunk 1 into registers (never padded) ----
    u16x8 kr[2], vr[2];
    #pragma unroll
    for (int p = 0; p < 2; ++p) {
        const int id = tid + p * 512;
        kr[p] = *(const u16x8*)(kbase + (size_t)(tkc1 + (id >> 3)) * CC + (id & 7) * 8);
        vr[p] = *(const u16x8*)(vbase + (size_t)(tkc1 + (id & 127)) * CC + (id >> 7) * 8);
    }
    __syncthreads();

    CHUNK(tkc0);
    __syncthreads();            // all chunk-0 reads of kn/vT/Pl complete

    // ---- write chunk 1 from registers ----
    #pragma unroll
    for (int p = 0; p < 2; ++p) {
        const int id = tid + p * 512;
        *(u16x8*)&kn[(id >> 3) * KP + (id & 7) * 8] = kr[p];
    }
    #pragma unroll
    for (int p = 0; p < 2; ++p) {
        const int id = tid + p * 512;
        const int key = id & 127, dc = id >> 7;
        #pragma unroll
        for (int e = 0; e < 8; ++e) vT[(dc * 8 + e) * VP + key] = vr[p][e];
    }
    __syncthreads();

    CHUNK(tkc1);

    // ---- finalize ----
    float inv[4];
    #pragma unroll
    for (int j = 0; j < 4; ++j) {
        l_run[j] += __shfl_xor(l_run[j], 1);
        l_run[j] += __shfl_xor(l_run[j], 2);
        l_run[j] += __shfl_xor(l_run[j], 4);
        l_run[j] += __shfl_xor(l_run[j], 8);
        inv[j] = 1.f / l_run[j];
    }
    u16* obase = o + rowbase * CC + h * 64;
    const int r0 = tq0 + wrow + gr * 4;
    #pragma unroll
    for (int n = 0; n < 4; ++n) {
        const int d = n * 16 + cl;
        #pragma unroll
        for (int j = 0; j < 4; ++j)
            obase[(size_t)(r0 + j) * CC + d] = f2bf(oacc[n][j] * inv[j]);
    }
}

extern "C" void kernel_launch(void* const* d_in, const int* in_sizes, int n_in,
                              void* d_out, int out_size, void* d_ws, size_t ws_size,
                              hipStream_t stream)
{
    (void)in_sizes; (void)n_in; (void)out_size;
    const float* x      = (const float*)d_in[0];   // [4,8192,512] fp32
    const float* w_qkv  = (const float*)d_in[1];   // [1536,512]   fp32
    const float* w_proj = (const float*)d_in[2];   // [512,512]    fp32
    const float* b_proj = (const float*)d_in[3];   // [512]        fp32
    float* out = (float*)d_out;                    // [4,8192,512] fp32

    const int BN = 4 * 8192;                       // 32768 rows
    const size_t qkv_b = (size_t)BN * 1536 * 2;    // 96 MiB
    const size_t xb_b  = (size_t)BN * 512 * 2;     // 32 MiB
    const size_t wq_b  = (size_t)1536 * 512 * 2;
    const size_t wp_b  = (size_t)512 * 512 * 2;

    uint8_t* p = (uint8_t*)d_ws;
    u16* qkv = (u16*)p;

    if (ws_size >= qkv_b + xb_b + wq_b + wp_b) {
        u16* xb  = (u16*)(p + qkv_b);
        u16* wqb = (u16*)(p + qkv_b + xb_b);
        u16* wpb = (u16*)(p + qkv_b + xb_b + wq_b);
        cvt3<<<1088, 256, 0, stream>>>(x, xb, w_qkv, wqb, w_proj, wpb);
        // qkv(bf16) = x @ w_qkv^T  (256^2 single-barrier pipeline) + K-norm
        gemm_pipe256<16, false, true, false><<<dim3(6, 128), 512, 0, stream>>>(
            xb, 512, wqb, 512, nullptr, qkv, 1536);
        attn_kernel<<<dim3(4 * 8 * 64), 512, 0, stream>>>(qkv, qkv);
        // out(fp32) = attnO @ w_proj^T + b_proj  (same pipeline, BIAS variant)
        gemm_pipe256<16, true, false, true><<<dim3(2, 128), 512, 0, stream>>>(
            qkv, 1536, wpb, 512, b_proj, out, 512);
    } else {
        // fallback: fp32 register-staged path
        gemm_bt_f32<true, false, true><<<dim3(12, BN / 128), 256, 0, stream>>>(
            x, 512, w_qkv, 512, nullptr, qkv, 1536, 512);
        attn_kernel<<<dim3(4 * 8 * 64), 512, 0, stream>>>(qkv, qkv);
        gemm_bt_f32<false, true, false><<<dim3(4, BN / 128), 256, 0, stream>>>(
            qkv, 1536, w_proj, 512, b_proj, out, 512, 512);
    }
}